// Round 9
// baseline (386.222 us; speedup 1.0000x reference)
//
#include <hip/hip_runtime.h>

#define LOG2E 1.4426950408889634f
#define LN2   0.6931471805599453f

namespace {
constexpr int B    = 64;
constexpr int T    = 2000;
constexpr int V    = 256;
constexpr int S    = 400;
constexpr int CHK  = 8;
constexpr int NCTP = 250;                       // chunks stored in G
constexpr int BSTR = 12;                        // bnd floats per chunk
constexpr int KP   = 408;                       // padded k rows (401 used)
constexpr size_t GELEM  = (size_t)B * NCTP * KP * 8;
constexpr size_t GBYTES = GELEM * 2;            // 104,448,000 B
constexpr int NW7 = 7;                          // fallback params
constexpr int NCT7 = 250;
constexpr int LSTR = 260;                       // gather LDS row stride
}

using h8 = __attribute__((ext_vector_type(8))) _Float16;

__device__ __forceinline__ float fexp2(float x){ return __builtin_amdgcn_exp2f(x); }
__device__ __forceinline__ float flog2(float x){ return __builtin_amdgcn_logf(x); }

__device__ __forceinline__ float wave_shr1(float x) {
  int v = __builtin_amdgcn_update_dpp(0, __builtin_bit_cast(int, x),
                                      0x138 /*WAVE_SHR1*/, 0xf, 0xf, true);
  return __builtin_bit_cast(float, v);
}
__device__ __forceinline__ int wave_shr1_i(int x) {
  return __builtin_amdgcn_update_dpp(0, x, 0x138, 0xf, 0xf, true);
}

// ---------------- gather pass: G[b][c][k][j] = fp16(exp(lp[b][1+8c+j][col_k]))
__global__ __launch_bounds__(512)
void ctc_gather_kernel(const float* __restrict__ logp,
                       const int* __restrict__ targets,
                       _Float16* __restrict__ G)
{
  const int tile = blockIdx.x;            // 32 tiles of 64 t-values
  const int b    = blockIdx.y;
  const int tid  = threadIdx.x;
  const int i0   = tile * 64;
  const float* lp = logp + (size_t)b * T * V;
  const int*   tg = targets + (size_t)b * S;

  __shared__ float ls[64 * LSTR];         // 65 KB; stride 260 -> b128 writes,
  __shared__ int   tgs[S];                // column reads spread 8 j-lanes
                                          // over banks {0,4,..,28} (<=2-way)
  for (int f = tid; f < 64 * 64; f += 512) {
    const int row = f >> 6, c4 = f & 63;
    int t = i0 + 1 + row; if (t > T - 1) t = T - 1;
    float4 v = ((const float4*)(lp + (size_t)t * V))[c4];
    *(float4*)&ls[row * LSTR + c4 * 4] = v;
  }
  for (int k = tid; k < S; k += 512) tgs[k] = tg[k];
  __syncthreads();

  const int w    = tid >> 6;
  const int lane = tid & 63;
  const int kk   = lane >> 3;             // k sub-index 0..7
  const int j    = lane & 7;              // t within chunk
  _Float16* gb = G + (size_t)b * NCTP * KP * 8;

  for (int idx = w; idx < 408; idx += 8) {   // 51 k-groups x 8 chunks
    const int kg = idx >> 3;
    const int cc = idx & 7;
    const int c  = tile * 8 + cc;
    if (c >= NCTP) continue;
    int k = kg * 8 + kk;
    const int e = (k < S) ? tgs[k] : 1;   // rows 400..407: blank/pad
    const float p = fexp2(ls[(cc * 8 + j) * LSTR + e] * LOG2E);
    gb[((size_t)c * KP + k) * 8 + j] = (_Float16)p;
  }
}

// ---------------- main: 8 waves per chain, 2 states/lane, prob domain,
// G prefetch depth 2 (loads issued two chunk-periods ahead) ----------------
__global__ __launch_bounds__(512)
void ctc_alpha8_kernel(const float* __restrict__ logp,
                       const int* __restrict__ targets,
                       const int* __restrict__ input_len,
                       const int* __restrict__ target_len,
                       const _Float16* __restrict__ G,
                       float* __restrict__ out)
{
  const int b    = blockIdx.x;
  const int tid  = threadIdx.x;
  const int w    = tid >> 6;
  const int lane = tid & 63;
  const bool lane0 = (lane == 0);
  const float* __restrict__ lp = logp + (size_t)b * T * V;
  const int il = input_len[b];
  const int tl = target_len[b];

  __shared__ float bnd[7][NCTP * BSTR];   // 84 KB boundary streams
  __shared__ int   cnt[7];
  __shared__ float afin[1024];

  if (tid < 7) cnt[tid] = 0;

  const int* tg = targets + (size_t)b * S;
  const int k1 = (tid < S) ? tid : (S - 1);
  const int e1 = tg[k1];
  const float sk1 = (k1 == 0 || e1 != tg[k1 - 1]) ? 1.0f : 0.0f;

  const _Float16* Gb = G + (size_t)b * NCTP * KP * 8;
  const size_t tokOff = (size_t)k1 * 8;
  const size_t blkOff = (size_t)400 * 8;

  __syncthreads();

  float a0 = 0.0f, a1 = 0.0f;
  int   E  = 0;
  if (tid == 0) {
    a0 = fexp2(lp[1]  * LOG2E);
    a1 = fexp2(lp[e1] * LOG2E);
  }

  // preload chunks 0 and 1 into the two rotating buffers
  h8 hA0 = *(const h8*)(Gb + tokOff);
  h8 hK0 = *(const h8*)(Gb + blkOff);
  h8 hA1 = *(const h8*)(Gb + (size_t)1 * KP * 8 + tokOff);
  h8 hK1 = *(const h8*)(Gb + (size_t)1 * KP * 8 + blkOff);

  const int NCH = (il - 1 + CHK - 1) / CHK;   // <= 250

  auto chunk_body = [&](int c, h8& hax, h8& hkx) {
    // consume current buffer
    float pa[CHK], pk[CHK];
    #pragma unroll
    for (int i = 0; i < CHK; ++i) { pa[i] = (float)hax[i]; pk[i] = (float)hkx[i]; }

    // reissue this buffer for chunk c+2 (two periods of latency cover)
    {
      int c2 = c + 2; if (c2 > NCTP - 1) c2 = NCTP - 1;
      const size_t base = (size_t)c2 * KP * 8;
      hax = *(const h8*)(Gb + base + tokOff);
      hkx = *(const h8*)(Gb + base + blkOff);
    }

    // consume boundary chunk
    float bq[CHK];
    int Ep = 0;
    if (w > 0) {
      while (__hip_atomic_load(&cnt[w - 1], __ATOMIC_ACQUIRE,
                               __HIP_MEMORY_SCOPE_WORKGROUP) < c + 1)
        __builtin_amdgcn_s_sleep(1);
      const float* src = &bnd[w - 1][c * BSTR];
      float4 q0 = *(const float4*)(src);
      float4 q1 = *(const float4*)(src + 4);
      bq[0]=q0.x; bq[1]=q0.y; bq[2]=q0.z; bq[3]=q0.w;
      bq[4]=q1.x; bq[5]=q1.y; bq[6]=q1.z; bq[7]=q1.w;
      Ep = __float_as_int(src[8]);
    } else {
      #pragma unroll
      for (int i = 0; i < CHK; ++i) bq[i] = 0.0f;
    }

    // exponent bookkeeping: 1 shfl + 3 DPP
    const float mz  = fmaxf(a0, a1);
    const int   E8  = __shfl_up(E, 8);
    const int   E1o = wave_shr1_i(E);
    const int   E9  = wave_shr1_i(E8);
    const float mz1 = wave_shr1(mz);
    if (mz == 0.0f) E = (lane < 8) ? Ep : E8;            // pre-adopt scale
    int E1 = (mz1 == 0.0f) ? ((lane <= 8) ? Ep : E9) : E1o;
    if (lane0) E1 = (w == 0) ? E : Ep;
    int d = E1 - E; d = d > 126 ? 126 : (d < -126 ? -126 : d);
    const float f = ldexpf(1.0f, d);
    const float a1s = a1;

    float pub[CHK];
    #pragma unroll
    for (int i = 0; i < CHK; ++i) {
      const int t = 1 + c * CHK + i;
      if (t < il) {                        // wave-uniform freeze predicate
        float hl = wave_shr1(a1);
        hl = lane0 ? bq[i] : hl;
        hl *= f;
        float s01 = a1 + a0;
        a1 = __builtin_fmaf(hl, sk1, s01) * pa[i];
        a0 = (a0 + hl) * pk[i];
      }
      pub[i] = a1;
    }

    // publish boundary (in this chunk's scale E) + release
    if (w < 7 && lane == 63) {
      float* dst = &bnd[w][c * BSTR];
      *(float4*)(dst)     = make_float4(a1s, pub[0], pub[1], pub[2]);
      *(float4*)(dst + 4) = make_float4(pub[3], pub[4], pub[5], pub[6]);
      dst[8] = __int_as_float(E);
      __hip_atomic_store(&cnt[w], c + 1, __ATOMIC_RELEASE,
                         __HIP_MEMORY_SCOPE_WORKGROUP);
    }

    // renormalize per lane
    {
      float m2 = fmaxf(a0, a1);
      int k = 0;
      (void)frexpf(m2, &k);                // m2==0 -> k=0
      a0 = ldexpf(a0, -k);
      a1 = ldexpf(a1, -k);
      E += k;
    }
  };

  for (int c = 0; c < NCH; c += 2) {
    chunk_body(c, hA0, hK0);
    if (c + 1 < NCH) chunk_body(c + 1, hA1, hK1);
  }

  afin[2 * tid]     = flog2(a0) + (float)E;
  afin[2 * tid + 1] = flog2(a1) + (float)E;
  __syncthreads();

  if (tid == 0) {
    const float x = afin[2 * tl];
    const float y = afin[2 * tl - 1];
    const float m = fmaxf(x, y);
    const float ll = (m + flog2(fexp2(x - m) + fexp2(y - m))) * LN2;
    float loss = -ll;
    if (!(loss < 1e29f)) loss = 0.0f;
    atomicAdd(out, loss / ((float)tl * (float)B));
  }
}

// ---------------- fallback: round-6 kernel (validated), if ws too small -----
__global__ __launch_bounds__(NW7 * 64)
void ctc_alpha7_kernel(const float* __restrict__ logp,
                       const int* __restrict__ targets,
                       const int* __restrict__ input_len,
                       const int* __restrict__ target_len,
                       float* __restrict__ out)
{
  const int b    = blockIdx.x;
  const int tid  = threadIdx.x;
  const int w    = tid >> 6;
  const int lane = tid & 63;
  const bool lane0 = (lane == 0);
  const float* __restrict__ lp = logp + (size_t)b * T * V;
  const int il = input_len[b];
  const int tl = target_len[b];
  const int Lb = 2 * tl + 1;

  __shared__ float bnd[NW7 - 1][NCT7 * BSTR];
  __shared__ int   cnt[NW7 - 1];
  __shared__ float pblk[T];
  __shared__ float afin[NW7 * 64 * 2];

  if (tid < NW7 - 1) cnt[tid] = 0;

  const int* tg = targets + (size_t)b * S;
  const int k1 = (tid < S) ? tid : (S - 1);
  const int e1 = tg[k1];
  const float sk1 = (k1 == 0 || e1 != tg[k1 - 1]) ? 1.0f : 0.0f;

  for (int i = tid; i < T; i += NW7 * 64) {
    int t = (i + 1 < T) ? (i + 1) : (T - 1);
    pblk[i] = fexp2(lp[(size_t)t * V + 1] * LOG2E);
  }
  __syncthreads();

  const bool active = (w * 128) < Lb;
  if (active) {
    float a0 = 0.0f, a1 = 0.0f;
    int   E  = 0;
    if (tid == 0) { a0 = fexp2(lp[1] * LOG2E); a1 = fexp2(lp[e1] * LOG2E); }

    float tokL[CHK];
    #pragma unroll
    for (int i = 0; i < CHK; ++i) tokL[i] = lp[(size_t)(1 + i) * V + e1];

    const int NCH = (il - 1 + CHK - 1) / CHK;
    for (int c = 0; c < NCH; ++c) {
      const int t0 = 1 + c * CHK;
      float tokP[CHK];
      #pragma unroll
      for (int i = 0; i < CHK; ++i) tokP[i] = fexp2(tokL[i] * LOG2E);
      float nl[CHK];
      if (c + 1 < NCT7) {
        #pragma unroll
        for (int i = 0; i < CHK; ++i) {
          int tt = t0 + CHK + i; if (tt > T - 1) tt = T - 1;
          nl[i] = lp[(size_t)tt * V + e1];
        }
      }
      float pbk[CHK];
      {
        float4 q0 = *(const float4*)&pblk[c * CHK];
        float4 q1 = *(const float4*)&pblk[c * CHK + 4];
        pbk[0]=q0.x; pbk[1]=q0.y; pbk[2]=q0.z; pbk[3]=q0.w;
        pbk[4]=q1.x; pbk[5]=q1.y; pbk[6]=q1.z; pbk[7]=q1.w;
      }
      float bq[CHK];
      int Ep = 0;
      if (w > 0) {
        while (__hip_atomic_load(&cnt[w - 1], __ATOMIC_ACQUIRE,
                                 __HIP_MEMORY_SCOPE_WORKGROUP) < c + 1)
          __builtin_amdgcn_s_sleep(1);
        const float* src = &bnd[w - 1][c * BSTR];
        float4 q0 = *(const float4*)(src);
        float4 q1 = *(const float4*)(src + 4);
        bq[0]=q0.x; bq[1]=q0.y; bq[2]=q0.z; bq[3]=q0.w;
        bq[4]=q1.x; bq[5]=q1.y; bq[6]=q1.z; bq[7]=q1.w;
        Ep = __float_as_int(src[8]);
      } else {
        #pragma unroll
        for (int i = 0; i < CHK; ++i) bq[i] = 0.0f;
      }
      const float mz  = fmaxf(a0, a1);
      const int   E1o = __shfl_up(E, 1);
      const int   E8  = __shfl_up(E, 8);
      const int   E9  = __shfl_up(E, 9);
      const float mz1 = __shfl_up(mz, 1);
      if (mz == 0.0f) E = (lane < 8) ? Ep : E8;
      int E1 = (mz1 == 0.0f) ? ((lane <= 8) ? Ep : E9) : E1o;
      if (lane0) E1 = (w == 0) ? E : Ep;
      int d = E1 - E; d = d > 126 ? 126 : (d < -126 ? -126 : d);
      const float f = ldexpf(1.0f, d);
      const float a1s = a1;
      float pub[CHK];
      #pragma unroll
      for (int i = 0; i < CHK; ++i) {
        const int t = t0 + i;
        if (t < il) {
          float hl = wave_shr1(a1);
          hl = lane0 ? bq[i] : hl;
          hl *= f;
          float s01 = a1 + a0;
          a1 = __builtin_fmaf(hl, sk1, s01) * tokP[i];
          a0 = (a0 + hl) * pbk[i];
        }
        pub[i] = a1;
      }
      if (w < NW7 - 1 && lane == 63) {
        float* dst = &bnd[w][c * BSTR];
        dst[0] = a1s;
        #pragma unroll
        for (int i = 0; i < CHK - 1; ++i) dst[1 + i] = pub[i];
        dst[8] = __int_as_float(E);
        __hip_atomic_store(&cnt[w], c + 1, __ATOMIC_RELEASE,
                           __HIP_MEMORY_SCOPE_WORKGROUP);
      }
      {
        float m2 = fmaxf(a0, a1);
        int k = 0;
        (void)frexpf(m2, &k);
        a0 = ldexpf(a0, -k);
        a1 = ldexpf(a1, -k);
        E += k;
      }
      #pragma unroll
      for (int i = 0; i < CHK; ++i) tokL[i] = nl[i];
    }
    afin[2 * tid]     = flog2(a0) + (float)E;
    afin[2 * tid + 1] = flog2(a1) + (float)E;
  }
  __syncthreads();

  if (tid == 0) {
    const float x = afin[2 * tl];
    const float y = afin[2 * tl - 1];
    const float m = fmaxf(x, y);
    const float ll = (m + flog2(fexp2(x - m) + fexp2(y - m))) * LN2;
    float loss = -ll;
    if (!(loss < 1e29f)) loss = 0.0f;
    atomicAdd(out, loss / ((float)tl * (float)B));
  }
}

__global__ void ctc_zero_kernel(float* __restrict__ out) { out[0] = 0.0f; }

extern "C" void kernel_launch(void* const* d_in, const int* in_sizes, int n_in,
                              void* d_out, int out_size, void* d_ws, size_t ws_size,
                              hipStream_t stream) {
  const float* logp    = (const float*)d_in[0];
  const int*   targets = (const int*)d_in[1];
  const int*   il      = (const int*)d_in[2];
  const int*   tl      = (const int*)d_in[3];
  float* out = (float*)d_out;

  ctc_zero_kernel<<<1, 1, 0, stream>>>(out);
  if (ws_size >= GBYTES) {
    _Float16* G = (_Float16*)d_ws;
    ctc_gather_kernel<<<dim3(32, B), 512, 0, stream>>>(logp, targets, G);
    ctc_alpha8_kernel<<<B, 512, 0, stream>>>(logp, targets, il, tl, G, out);
  } else {
    ctc_alpha7_kernel<<<B, NW7 * 64, 0, stream>>>(logp, targets, il, tl, out);
  }
}

// Round 11
// 331.410 us; speedup vs baseline: 1.1654x; 1.1654x over previous
//
#include <hip/hip_runtime.h>

#define LOG2E 1.4426950408889634f
#define LN2   0.6931471805599453f

namespace {
constexpr int B    = 64;
constexpr int T    = 2000;
constexpr int V    = 256;
constexpr int S    = 400;
constexpr int CHK  = 8;
constexpr int NCTP = 250;                 // chunks stored in G
constexpr int BSTR = 20;                  // bnd floats per chunk (bwd needs 17)
constexpr int KP   = 408;                 // padded k rows (401 used)
constexpr size_t GELEM  = (size_t)B * NCTP * KP * 8;
constexpr size_t GBYTES = GELEM * 2;      // 104,448,000 B
constexpr size_t LAOFF  = GBYTES / 4;     // float offset of la in ws
constexpr size_t LGOFF  = LAOFF + 64 * 1024;
constexpr size_t REQBYTES = GBYTES + 2 * 64 * 1024 * 4;   // 104,972,288
constexpr int LSTR = 260;                 // gather LDS row stride
constexpr int NW7  = 7;                   // fallback params
constexpr int NCT7 = 250;
constexpr int BST7 = 12;
}

using h8 = __attribute__((ext_vector_type(8))) _Float16;

__device__ __forceinline__ float fexp2(float x){ return __builtin_amdgcn_exp2f(x); }
__device__ __forceinline__ float flog2(float x){ return __builtin_amdgcn_logf(x); }

// lane i <- lane i-1 (0 for lane 0)
__device__ __forceinline__ float wave_shr1(float x) {
  int v = __builtin_amdgcn_update_dpp(0, __builtin_bit_cast(int, x),
                                      0x138, 0xf, 0xf, true);
  return __builtin_bit_cast(float, v);
}
__device__ __forceinline__ int wave_shr1_i(int x) {
  return __builtin_amdgcn_update_dpp(0, x, 0x138, 0xf, 0xf, true);
}
// lane i <- lane i+1 (0 for lane 63)
__device__ __forceinline__ float wave_shl1(float x) {
  int v = __builtin_amdgcn_update_dpp(0, __builtin_bit_cast(int, x),
                                      0x130, 0xf, 0xf, true);
  return __builtin_bit_cast(float, v);
}
__device__ __forceinline__ int wave_shl1_i(int x) {
  return __builtin_amdgcn_update_dpp(0, x, 0x130, 0xf, 0xf, true);
}

// ---------------- gather: G[b][c][k][j] = fp16(exp(lp[b][1+8c+j][col_k])) ----
__global__ __launch_bounds__(512)
void ctc_gather_kernel(const float* __restrict__ logp,
                       const int* __restrict__ targets,
                       _Float16* __restrict__ G)
{
  const int tile = blockIdx.x;            // 32 tiles of 64 t-values
  const int b    = blockIdx.y;
  const int tid  = threadIdx.x;
  const int i0   = tile * 64;
  const float* lp = logp + (size_t)b * T * V;
  const int*   tg = targets + (size_t)b * S;

  __shared__ float ls[64 * LSTR];         // 65 KB
  __shared__ int   tgs[S];

  for (int f = tid; f < 64 * 64; f += 512) {
    const int row = f >> 6, c4 = f & 63;
    int t = i0 + 1 + row; if (t > T - 1) t = T - 1;
    float4 v = ((const float4*)(lp + (size_t)t * V))[c4];
    *(float4*)&ls[row * LSTR + c4 * 4] = v;
  }
  for (int k = tid; k < S; k += 512) tgs[k] = tg[k];
  __syncthreads();

  const int w    = tid >> 6;
  const int lane = tid & 63;
  _Float16* gb = G + (size_t)b * NCTP * KP * 8;

  // 7 k-blocks x 8 chunks; lane produces 8 j-values for one k (16B store)
  for (int it = w; it < 56; it += 8) {
    const int kb = it >> 3;
    const int cc = it & 7;
    const int c  = tile * 8 + cc;
    if (c >= NCTP) continue;
    const int k = kb * 64 + lane;
    if (k >= KP) continue;
    const int e = (k < S) ? tgs[k] : 1;   // rows 400..407: blank/pad
    h8 hv;
    #pragma unroll
    for (int j = 0; j < 8; ++j)
      hv[j] = (_Float16)fexp2(ls[(cc * 8 + j) * LSTR + e] * LOG2E);
    *(h8*)(gb + ((size_t)c * KP + k) * 8) = hv;
  }
}

// ---------------- fwd/bwd meet-in-middle: 4 waves, 4 states/lane ------------
// dir=blockIdx.y: 0 = forward alpha (t=1..m), 1 = backward gamma (rows
// il-1..m+1). P(l|x) = sum_s alpha_m(s)*gamma_m(s). Prob-domain recurrence
// with per-lane exponent E (validated r6/r7 scheme). FIX vs r10: backward
// interior DPP halos must be rescaled by f (neighbor scale), exactly like
// the forward — previously f was applied only at lane63.
__global__ __launch_bounds__(256)
void ctc_fb_kernel(const float* __restrict__ logp,
                   const int* __restrict__ targets,
                   const int* __restrict__ input_len,
                   const int* __restrict__ target_len,
                   const _Float16* __restrict__ G,
                   float* __restrict__ la,
                   float* __restrict__ lg)
{
  const int b    = blockIdx.x;
  const int dir  = blockIdx.y;
  const int tid  = threadIdx.x;
  const int w    = tid >> 6;
  const int lane = tid & 63;
  const bool lane0  = (lane == 0);
  const bool lane63 = (lane == 63);
  const float* __restrict__ lp = logp + (size_t)b * T * V;
  const int il = input_len[b];
  const int tl = target_len[b];
  const int m  = il >> 1;

  __shared__ float bnd[3][NCTP * BSTR];   // 60 KB
  __shared__ int   cnt[3];
  if (tid < 3) cnt[tid] = 0;

  const int* tg = targets + (size_t)b * S;
  int ka = 2 * tid;     if (ka > S - 1) ka = S - 1;
  int kb = 2 * tid + 1; if (kb > S - 1) kb = S - 1;
  int kc = 2 * tid + 2; if (kc > S - 1) kc = S - 1;
  const int ea = tg[ka];
  const int eb = tg[kb];
  const int ec = tg[kc];
  const float ska = (ka == 0 || ea != tg[ka - 1]) ? 1.0f : 0.0f;
  const float skb = (eb != ea) ? 1.0f : 0.0f;
  const float skA = (eb != ea) ? 1.0f : 0.0f;
  const float skB = (ec != eb) ? 1.0f : 0.0f;

  const _Float16* Gb = G + (size_t)b * NCTP * KP * 8;
  const size_t offA = (size_t)ka * 8;
  const size_t offB = (size_t)kb * 8;
  const size_t offK = (size_t)400 * 8;

  __syncthreads();   // cnt visible

  if (dir == 0) {
    // ======================= FORWARD =======================
    float a0 = 0.0f, a1 = 0.0f, a2 = 0.0f, a3 = 0.0f;
    int   E  = 0;
    if (tid == 0) {
      a0 = fexp2(lp[1]  * LOG2E);
      a1 = fexp2(lp[ea] * LOG2E);
    }
    h8 hA = *(const h8*)(Gb + offA);
    h8 hB = *(const h8*)(Gb + offB);
    h8 hK = *(const h8*)(Gb + offK);

    const int NCH = (m + 7) >> 3;
    for (int c = 0; c < NCH; ++c) {
      float pa[CHK], pb[CHK], pk[CHK];
      #pragma unroll
      for (int i = 0; i < CHK; ++i) {
        pa[i] = (float)hA[i]; pb[i] = (float)hB[i]; pk[i] = (float)hK[i];
      }
      { // prefetch next chunk
        int c2 = c + 1; if (c2 > NCTP - 1) c2 = NCTP - 1;
        const size_t base = (size_t)c2 * KP * 8;
        hA = *(const h8*)(Gb + base + offA);
        hB = *(const h8*)(Gb + base + offB);
        hK = *(const h8*)(Gb + base + offK);
      }
      float bq[CHK];
      int Ep = 0;
      if (w > 0) {
        while (__hip_atomic_load(&cnt[w - 1], __ATOMIC_ACQUIRE,
                                 __HIP_MEMORY_SCOPE_WORKGROUP) < c + 1)
          __builtin_amdgcn_s_sleep(1);
        const float* src = &bnd[w - 1][c * BSTR];
        float4 q0 = *(const float4*)(src);
        float4 q1 = *(const float4*)(src + 4);
        bq[0]=q0.x; bq[1]=q0.y; bq[2]=q0.z; bq[3]=q0.w;
        bq[4]=q1.x; bq[5]=q1.y; bq[6]=q1.z; bq[7]=q1.w;
        Ep = __float_as_int(src[8]);
      } else {
        #pragma unroll
        for (int i = 0; i < CHK; ++i) bq[i] = 0.0f;
      }
      const float mz  = fmaxf(fmaxf(a0, a1), fmaxf(a2, a3));
      const int   E4  = __shfl_up(E, 4);
      const int   E1o = wave_shr1_i(E);
      const int   E5  = wave_shr1_i(E4);
      const float mz1 = wave_shr1(mz);
      if (mz == 0.0f) E = (lane < 4) ? Ep : E4;
      int E1 = (mz1 == 0.0f) ? ((lane <= 4) ? Ep : E5) : E1o;
      if (lane0) E1 = (w == 0) ? E : Ep;
      int d = E1 - E; d = d > 126 ? 126 : (d < -126 ? -126 : d);
      const float f = ldexpf(1.0f, d);
      const float a3s = a3;

      float pub[CHK];
      #pragma unroll
      for (int i = 0; i < CHK; ++i) {
        const int t = 1 + c * CHK + i;
        if (t <= m) {
          float hl = wave_shr1(a3);
          hl = lane0 ? bq[i] : hl;
          hl *= f;
          float t3 = a3 + a2;  a3 = __builtin_fmaf(a1, skb, t3) * pb[i];
          a2 = (a2 + a1) * pk[i];
          float t1 = a1 + a0;  a1 = __builtin_fmaf(hl, ska, t1) * pa[i];
          a0 = (a0 + hl) * pk[i];
        }
        pub[i] = a3;
      }
      if (w < 3 && lane63) {
        float* dst = &bnd[w][c * BSTR];
        *(float4*)(dst)     = make_float4(a3s, pub[0], pub[1], pub[2]);
        *(float4*)(dst + 4) = make_float4(pub[3], pub[4], pub[5], pub[6]);
        dst[8] = __int_as_float(E);
        __hip_atomic_store(&cnt[w], c + 1, __ATOMIC_RELEASE,
                           __HIP_MEMORY_SCOPE_WORKGROUP);
      }
      {
        float m2 = fmaxf(fmaxf(a0, a1), fmaxf(a2, a3));
        int k = 0; (void)frexpf(m2, &k);
        a0 = ldexpf(a0, -k); a1 = ldexpf(a1, -k);
        a2 = ldexpf(a2, -k); a3 = ldexpf(a3, -k);
        E += k;
      }
    }
    float* dst = la + (size_t)b * 1024 + 4 * tid;
    dst[0] = flog2(a0) + (float)E;
    dst[1] = flog2(a1) + (float)E;
    dst[2] = flog2(a2) + (float)E;
    dst[3] = flog2(a3) + (float)E;
  } else {
    // ======================= BACKWARD =======================
    const int s0 = 4 * tid;
    float g0 = (s0 + 0 == 2 * tl - 1 || s0 + 0 == 2 * tl) ? 1.0f : 0.0f;
    float g1 = (s0 + 1 == 2 * tl - 1 || s0 + 1 == 2 * tl) ? 1.0f : 0.0f;
    float g2 = (s0 + 2 == 2 * tl - 1 || s0 + 2 == 2 * tl) ? 1.0f : 0.0f;
    float g3 = (s0 + 3 == 2 * tl - 1 || s0 + 3 == 2 * tl) ? 1.0f : 0.0f;
    int   E  = 0;

    const int c_hi = (il - 2) >> 3;
    const int c_lo = m >> 3;
    h8 hA = *(const h8*)(Gb + (size_t)c_hi * KP * 8 + offA);
    h8 hB = *(const h8*)(Gb + (size_t)c_hi * KP * 8 + offB);
    h8 hK = *(const h8*)(Gb + (size_t)c_hi * KP * 8 + offK);

    for (int c = c_hi; c >= c_lo; --c) {
      float pa[CHK], pb[CHK], pk[CHK];
      #pragma unroll
      for (int i = 0; i < CHK; ++i) {
        pa[i] = (float)hA[i]; pb[i] = (float)hB[i]; pk[i] = (float)hK[i];
      }
      { // prefetch next (descending)
        int c2 = c - 1; if (c2 < 0) c2 = 0;
        const size_t base = (size_t)c2 * KP * 8;
        hA = *(const h8*)(Gb + base + offA);
        hB = *(const h8*)(Gb + base + offB);
        hK = *(const h8*)(Gb + base + offK);
      }
      float bq0[CHK], bq1[CHK];
      int Ep = 0;
      if (w < 3) {
        while (__hip_atomic_load(&cnt[w], __ATOMIC_ACQUIRE,
                                 __HIP_MEMORY_SCOPE_WORKGROUP) < c_hi - c + 1)
          __builtin_amdgcn_s_sleep(1);
        const float* src = &bnd[w][c * BSTR];
        float4 q0 = *(const float4*)(src);
        float4 q1 = *(const float4*)(src + 4);
        float4 q2 = *(const float4*)(src + 8);
        float4 q3 = *(const float4*)(src + 12);
        bq0[0]=q0.x; bq0[1]=q0.y; bq0[2]=q0.z; bq0[3]=q0.w;
        bq0[4]=q1.x; bq0[5]=q1.y; bq0[6]=q1.z; bq0[7]=q1.w;
        bq1[0]=q2.x; bq1[1]=q2.y; bq1[2]=q2.z; bq1[3]=q2.w;
        bq1[4]=q3.x; bq1[5]=q3.y; bq1[6]=q3.z; bq1[7]=q3.w;
        Ep = __float_as_int(src[16]);
      } else {
        #pragma unroll
        for (int i = 0; i < CHK; ++i) { bq0[i] = 0.0f; bq1[i] = 0.0f; }
      }
      const float mz  = fmaxf(fmaxf(g0, g1), fmaxf(g2, g3));
      const int   E4  = __shfl_down(E, 4);
      const int   E1o = wave_shl1_i(E);
      const int   E5  = wave_shl1_i(E4);
      const float mzN = wave_shl1(mz);
      if (mz == 0.0f) E = (lane >= 60) ? Ep : E4;
      int E1 = (mzN == 0.0f) ? ((lane >= 59) ? Ep : E5) : E1o;
      if (lane63) E1 = (w == 3) ? E : Ep;
      int d = E1 - E; d = d > 126 ? 126 : (d < -126 ? -126 : d);
      const float f = ldexpf(1.0f, d);

      float pub0[CHK], pub1[CHK];
      #pragma unroll
      for (int i = 0; i < CHK; ++i) { pub0[i] = 0.0f; pub1[i] = 0.0f; }
      #pragma unroll
      for (int jj = 0; jj < CHK; ++jj) {
        const int j = CHK - 1 - jj;
        const int row = 1 + c * CHK + j;    // emission row (= t+1)
        if (row > m && row < il) {          // wave-uniform predicate
          float pg0 = g0 * pk[j];
          float pg1 = g1 * pa[j];
          float pg2 = g2 * pk[j];
          float pg3 = g3 * pb[j];
          float h0 = wave_shl1(pg0);
          float h1 = wave_shl1(pg1);
          h0 = lane63 ? bq0[j] : h0;        // FIX: rescale ALL halos by f,
          h1 = lane63 ? bq1[j] : h1;        // not just the lane63 boundary
          h0 *= f;
          h1 *= f;
          pub0[j] = pg0; pub1[j] = pg1;
          g3 = __builtin_fmaf(h1, skB, pg3 + h0);
          g2 = pg3 + pg2;
          g1 = __builtin_fmaf(pg3, skA, pg1 + pg2);
          g0 = pg0 + pg1;
        }
      }
      if (w > 0 && lane0) {
        float* dst = &bnd[w - 1][c * BSTR];
        *(float4*)(dst)      = make_float4(pub0[0], pub0[1], pub0[2], pub0[3]);
        *(float4*)(dst + 4)  = make_float4(pub0[4], pub0[5], pub0[6], pub0[7]);
        *(float4*)(dst + 8)  = make_float4(pub1[0], pub1[1], pub1[2], pub1[3]);
        *(float4*)(dst + 12) = make_float4(pub1[4], pub1[5], pub1[6], pub1[7]);
        dst[16] = __int_as_float(E);
        __hip_atomic_store(&cnt[w - 1], c_hi - c + 1, __ATOMIC_RELEASE,
                           __HIP_MEMORY_SCOPE_WORKGROUP);
      }
      {
        float m2 = fmaxf(fmaxf(g0, g1), fmaxf(g2, g3));
        int k = 0; (void)frexpf(m2, &k);
        g0 = ldexpf(g0, -k); g1 = ldexpf(g1, -k);
        g2 = ldexpf(g2, -k); g3 = ldexpf(g3, -k);
        E += k;
      }
    }
    float* dst = lg + (size_t)b * 1024 + 4 * tid;
    dst[0] = flog2(g0) + (float)E;
    dst[1] = flog2(g1) + (float)E;
    dst[2] = flog2(g2) + (float)E;
    dst[3] = flog2(g3) + (float)E;
  }
}

// ---------------- merge: loss_b = -ln sum_{s<Lb} 2^(la+lg), mean ------------
__global__ __launch_bounds__(64)
void ctc_merge_kernel(const float* __restrict__ la,
                      const float* __restrict__ lg,
                      const int* __restrict__ target_len,
                      float* __restrict__ out)
{
  const int b    = blockIdx.x;
  const int lane = threadIdx.x;
  const int tl = target_len[b];
  const int Lb = 2 * tl + 1;
  const float* A  = la + (size_t)b * 1024;
  const float* Gm = lg + (size_t)b * 1024;

  float vs[16];
  float vmax = -1e30f;
  #pragma unroll
  for (int r = 0; r < 16; ++r) {
    const int s = lane + 64 * r;
    float x = A[s] + Gm[s];
    x = (s < Lb) ? x : -1e30f;
    vs[r] = x;
    vmax = fmaxf(vmax, x);
  }
  #pragma unroll
  for (int o = 32; o > 0; o >>= 1) vmax = fmaxf(vmax, __shfl_xor(vmax, o, 64));
  float sum = 0.0f;
  #pragma unroll
  for (int r = 0; r < 16; ++r) sum += fexp2(vs[r] - vmax);
  #pragma unroll
  for (int o = 32; o > 0; o >>= 1) sum += __shfl_xor(sum, o, 64);
  if (lane == 0) {
    const float ll = (vmax + flog2(sum)) * LN2;
    float loss = -ll;
    if (!(loss < 1e29f)) loss = 0.0f;
    atomicAdd(out, loss / ((float)tl * (float)B));
  }
}

// ---------------- fallback: round-6 kernel (validated), if ws too small -----
__global__ __launch_bounds__(NW7 * 64)
void ctc_alpha7_kernel(const float* __restrict__ logp,
                       const int* __restrict__ targets,
                       const int* __restrict__ input_len,
                       const int* __restrict__ target_len,
                       float* __restrict__ out)
{
  const int b    = blockIdx.x;
  const int tid  = threadIdx.x;
  const int w    = tid >> 6;
  const int lane = tid & 63;
  const bool lane0 = (lane == 0);
  const float* __restrict__ lp = logp + (size_t)b * T * V;
  const int il = input_len[b];
  const int tl = target_len[b];
  const int Lb = 2 * tl + 1;

  __shared__ float bnd[NW7 - 1][NCT7 * BST7];
  __shared__ int   cnt[NW7 - 1];
  __shared__ float pblk[T];
  __shared__ float afin[NW7 * 64 * 2];

  if (tid < NW7 - 1) cnt[tid] = 0;

  const int* tg = targets + (size_t)b * S;
  const int k1 = (tid < S) ? tid : (S - 1);
  const int e1 = tg[k1];
  const float sk1 = (k1 == 0 || e1 != tg[k1 - 1]) ? 1.0f : 0.0f;

  for (int i = tid; i < T; i += NW7 * 64) {
    int t = (i + 1 < T) ? (i + 1) : (T - 1);
    pblk[i] = fexp2(lp[(size_t)t * V + 1] * LOG2E);
  }
  __syncthreads();

  const bool active = (w * 128) < Lb;
  if (active) {
    float a0 = 0.0f, a1 = 0.0f;
    int   E  = 0;
    if (tid == 0) { a0 = fexp2(lp[1] * LOG2E); a1 = fexp2(lp[e1] * LOG2E); }

    float tokL[CHK];
    #pragma unroll
    for (int i = 0; i < CHK; ++i) tokL[i] = lp[(size_t)(1 + i) * V + e1];

    const int NCH = (il - 1 + CHK - 1) / CHK;
    for (int c = 0; c < NCH; ++c) {
      const int t0 = 1 + c * CHK;
      float tokP[CHK];
      #pragma unroll
      for (int i = 0; i < CHK; ++i) tokP[i] = fexp2(tokL[i] * LOG2E);
      float nl[CHK];
      if (c + 1 < NCT7) {
        #pragma unroll
        for (int i = 0; i < CHK; ++i) {
          int tt = t0 + CHK + i; if (tt > T - 1) tt = T - 1;
          nl[i] = lp[(size_t)tt * V + e1];
        }
      }
      float pbk[CHK];
      {
        float4 q0 = *(const float4*)&pblk[c * CHK];
        float4 q1 = *(const float4*)&pblk[c * CHK + 4];
        pbk[0]=q0.x; pbk[1]=q0.y; pbk[2]=q0.z; pbk[3]=q0.w;
        pbk[4]=q1.x; pbk[5]=q1.y; pbk[6]=q1.z; pbk[7]=q1.w;
      }
      float bq[CHK];
      int Ep = 0;
      if (w > 0) {
        while (__hip_atomic_load(&cnt[w - 1], __ATOMIC_ACQUIRE,
                                 __HIP_MEMORY_SCOPE_WORKGROUP) < c + 1)
          __builtin_amdgcn_s_sleep(1);
        const float* src = &bnd[w - 1][c * BST7];
        float4 q0 = *(const float4*)(src);
        float4 q1 = *(const float4*)(src + 4);
        bq[0]=q0.x; bq[1]=q0.y; bq[2]=q0.z; bq[3]=q0.w;
        bq[4]=q1.x; bq[5]=q1.y; bq[6]=q1.z; bq[7]=q1.w;
        Ep = __float_as_int(src[8]);
      } else {
        #pragma unroll
        for (int i = 0; i < CHK; ++i) bq[i] = 0.0f;
      }
      const float mz  = fmaxf(a0, a1);
      const int   E1o = __shfl_up(E, 1);
      const int   E8  = __shfl_up(E, 8);
      const int   E9  = __shfl_up(E, 9);
      const float mz1 = __shfl_up(mz, 1);
      if (mz == 0.0f) E = (lane < 8) ? Ep : E8;
      int E1 = (mz1 == 0.0f) ? ((lane <= 8) ? Ep : E9) : E1o;
      if (lane0) E1 = (w == 0) ? E : Ep;
      int d = E1 - E; d = d > 126 ? 126 : (d < -126 ? -126 : d);
      const float f = ldexpf(1.0f, d);
      const float a1s = a1;
      float pub[CHK];
      #pragma unroll
      for (int i = 0; i < CHK; ++i) {
        const int t = t0 + i;
        if (t < il) {
          float hl = wave_shr1(a1);
          hl = lane0 ? bq[i] : hl;
          hl *= f;
          float s01 = a1 + a0;
          a1 = __builtin_fmaf(hl, sk1, s01) * tokP[i];
          a0 = (a0 + hl) * pbk[i];
        }
        pub[i] = a1;
      }
      if (w < NW7 - 1 && lane == 63) {
        float* dst = &bnd[w][c * BST7];
        dst[0] = a1s;
        #pragma unroll
        for (int i = 0; i < CHK - 1; ++i) dst[1 + i] = pub[i];
        dst[8] = __int_as_float(E);
        __hip_atomic_store(&cnt[w], c + 1, __ATOMIC_RELEASE,
                           __HIP_MEMORY_SCOPE_WORKGROUP);
      }
      {
        float m2 = fmaxf(a0, a1);
        int k = 0;
        (void)frexpf(m2, &k);
        a0 = ldexpf(a0, -k);
        a1 = ldexpf(a1, -k);
        E += k;
      }
      #pragma unroll
      for (int i = 0; i < CHK; ++i) tokL[i] = nl[i];
    }
    afin[2 * tid]     = flog2(a0) + (float)E;
    afin[2 * tid + 1] = flog2(a1) + (float)E;
  }
  __syncthreads();

  if (tid == 0) {
    const float x = afin[2 * tl];
    const float y = afin[2 * tl - 1];
    const float mm = fmaxf(x, y);
    const float ll = (mm + flog2(fexp2(x - mm) + fexp2(y - mm))) * LN2;
    float loss = -ll;
    if (!(loss < 1e29f)) loss = 0.0f;
    atomicAdd(out, loss / ((float)tl * (float)B));
  }
}

__global__ void ctc_zero_kernel(float* __restrict__ out) { out[0] = 0.0f; }

extern "C" void kernel_launch(void* const* d_in, const int* in_sizes, int n_in,
                              void* d_out, int out_size, void* d_ws, size_t ws_size,
                              hipStream_t stream) {
  const float* logp    = (const float*)d_in[0];
  const int*   targets = (const int*)d_in[1];
  const int*   il      = (const int*)d_in[2];
  const int*   tl      = (const int*)d_in[3];
  float* out = (float*)d_out;

  ctc_zero_kernel<<<1, 1, 0, stream>>>(out);
  if (ws_size >= REQBYTES) {
    _Float16* G  = (_Float16*)d_ws;
    float*    la = (float*)d_ws + LAOFF;
    float*    lg = (float*)d_ws + LGOFF;
    ctc_gather_kernel<<<dim3(32, B), 512, 0, stream>>>(logp, targets, G);
    ctc_fb_kernel<<<dim3(B, 2), 256, 0, stream>>>(logp, targets, il, tl, G, la, lg);
    ctc_merge_kernel<<<B, 64, 0, stream>>>(la, lg, tl, out);
  } else {
    ctc_alpha7_kernel<<<B, NW7 * 64, 0, stream>>>(logp, targets, il, tl, out);
  }
}